// Round 7
// baseline (115.601 us; speedup 1.0000x reference)
//
#include <hip/hip_runtime.h>
#include <cmath>

#define Bn 4
#define Hn 12
#define BH 48
#define Nn 8192
#define Dn 64

typedef float f32x4 __attribute__((ext_vector_type(4)));
typedef short bf16x8 __attribute__((ext_vector_type(8)));

__device__ __forceinline__ int swz(int d) { return ((d >> 2) & 7) << 3; }

// v_cvt_pk_bf16_f32: D[15:0]=bf16(lo), D[31:16]=bf16(hi)  (RNE)
__device__ __forceinline__ unsigned cvt_pk_bf16(float lo, float hi) {
    unsigned r;
    asm("v_cvt_pk_bf16_f32 %0, %1, %2" : "=v"(r) : "v"(lo), "v"(hi));
    return r;
}

// ---------------- Phase 1: partial KtV^T[e][d] = sum_n (rf*k)[n,d] * v[n,e] --
// rf = scale * m^2 / max(||k||, eps).  MFMA: A = V^T (rows e), B = K' (cols d),
// contraction n.  K,V staged transposed+swizzled in LDS as bf16.
// ch=64 -> grid 3072 blocks (12/CU): occupancy is grid-fed, latency hidden by
// inter-block TLP (round-3 structure was grid-starved at 3 blocks/CU).
__global__ __launch_bounds__(256) void ktv_kernel(
    const float* __restrict__ K, const float* __restrict__ V,
    const float* __restrict__ mask, float* __restrict__ partial,
    float scale, int ch)
{
    const int chunk = blockIdx.x, head = blockIdx.y;
    const int bb = head / Hn;
    const int rowsPer = Nn / ch;
    const int n0 = chunk * rowsPer;
    const float* Kp = K + ((size_t)head * Nn + n0) * Dn;
    const float* Vp = V + ((size_t)head * Nn + n0) * Dn;
    const float* mp = mask + (size_t)bb * Nn + n0;

    __shared__ __align__(16) ushort sKT[64 * 64];   // [d][n^swz(d)] bf16
    __shared__ __align__(16) ushort sVT[64 * 64];   // [e][n^swz(e)] bf16

    const int t = threadIdx.x;
    const int w = t >> 6, l = t & 63;
    const int g = t >> 4;            // row-group 0..15 (rows 4g..4g+3)
    const int c4 = (t & 15) << 2;    // d base for staging

    f32x4 acc[4] = {{0.f,0.f,0.f,0.f},{0.f,0.f,0.f,0.f},
                    {0.f,0.f,0.f,0.f},{0.f,0.f,0.f,0.f}};

    float4 kr[4], vr[4];
    float mk[4];
    #pragma unroll
    for (int s = 0; s < 4; ++s) {
        kr[s] = *(const float4*)(Kp + (size_t)(4*g + s) * Dn + c4);
        vr[s] = *(const float4*)(Vp + (size_t)(4*g + s) * Dn + c4);
        mk[s] = mp[4*g + s];
    }

    const int ntiles = rowsPer >> 6;          // 64-row tiles
    for (int tt = 0; tt < ntiles; ++tt) {
        float rf[4];
        #pragma unroll
        for (int s = 0; s < 4; ++s) {
            float ss = kr[s].x*kr[s].x + kr[s].y*kr[s].y
                     + kr[s].z*kr[s].z + kr[s].w*kr[s].w;
            #pragma unroll
            for (int off = 1; off < 16; off <<= 1) ss += __shfl_xor(ss, off, 64);
            rf[s] = scale * mk[s] * mk[s] / fmaxf(sqrtf(ss), 1e-12f);
        }

        __syncthreads();                      // previous tile consumed
        const float* krf = (const float*)kr;  // kr[s] comp j -> krf[4s+j]
        const float* vrf = (const float*)vr;
        #pragma unroll
        for (int j = 0; j < 4; ++j) {
            const int d = c4 + j;
            const int base = d * 64;
            const int sw = swz(d);
            const int p0 = (4*g)     ^ sw;    // even; swz only hits bits 3..5
            const int p2 = (4*g + 2) ^ sw;
            *(unsigned*)&sKT[base + p0] = cvt_pk_bf16(krf[j]     * rf[0], krf[4+j]  * rf[1]);
            *(unsigned*)&sKT[base + p2] = cvt_pk_bf16(krf[8+j]   * rf[2], krf[12+j] * rf[3]);
            *(unsigned*)&sVT[base + p0] = cvt_pk_bf16(vrf[j],            vrf[4+j]);
            *(unsigned*)&sVT[base + p2] = cvt_pk_bf16(vrf[8+j],          vrf[12+j]);
        }
        __syncthreads();

        if (tt + 1 < ntiles) {                // prefetch under MFMA
            const float* Kn = Kp + (size_t)(tt + 1) * 64 * Dn;
            const float* Vn = Vp + (size_t)(tt + 1) * 64 * Dn;
            #pragma unroll
            for (int s = 0; s < 4; ++s) {
                kr[s] = *(const float4*)(Kn + (size_t)(4*g + s) * Dn + c4);
                vr[s] = *(const float4*)(Vn + (size_t)(4*g + s) * Dn + c4);
                mk[s] = mp[(tt + 1) * 64 + 4*g + s];
            }
        }

        // wave w owns e-strip [16w,16w+16); 4 d-panels; contraction in 2 halves
        const int e   = (w << 4) + (l & 15);
        const int nsl = (l >> 4) << 3;        // k-slice start within 32-half
        const int swe = swz(e);
        #pragma unroll
        for (int h = 0; h < 2; ++h) {
            const bf16x8 a = *(const bf16x8*)&sVT[e * 64 + ((h*32 + nsl) ^ swe)];
            #pragma unroll
            for (int P = 0; P < 4; ++P) {
                const int d = (P << 4) + (l & 15);
                const bf16x8 bq = *(const bf16x8*)&sKT[d * 64 + ((h*32 + nsl) ^ swz(d))];
                acc[P] = __builtin_amdgcn_mfma_f32_16x16x32_bf16(a, bq, acc[P], 0, 0, 0);
            }
        }
    }

    // C layout: col = lane&15, row = 4*(lane>>4)+reg   (HW-verified)
    float* pp = partial + (size_t)(head * ch + chunk) * (Dn * Dn);
    #pragma unroll
    for (int P = 0; P < 4; ++P)
        #pragma unroll
        for (int r = 0; r < 4; ++r)
            pp[((w << 4) + ((l >> 4) << 2) + r) * 64 + (P << 4) + (l & 15)] = acc[P][r];
}

// ---------------- Phase 1b: reduce partials, emit bf16 KtV^T ----------------
__global__ __launch_bounds__(256) void ktv_reduce_kernel(
    const float* __restrict__ partial, ushort* __restrict__ ktvT, int ch)
{
    const int head = blockIdx.y;
    const int e = blockIdx.x * 256 + threadIdx.x;   // 0..4095
    const float* pp = partial + (size_t)head * ch * (Dn * Dn) + e;
    float s = 0.f;
    for (int c = 0; c < ch; ++c) s += pp[(size_t)c * (Dn * Dn)];
    unsigned u = __float_as_uint(s);
    u = (u + 0x7fffu + ((u >> 16) & 1u)) >> 16;     // RNE
    ktvT[(size_t)head * (Dn * Dn) + e] = (ushort)u;
}

// ---------------- Phase 2: Out = (inv(n)*q) @ KtV  (no LDS) -----------------
// A = Q rows (d contiguous), inv-norm folded into A pre-conversion.
// B = KtV^T rows from global (L2/L3-resident, 8 frags hoisted to registers).
__global__ __launch_bounds__(256) void qktv_kernel(
    const float* __restrict__ Q, const ushort* __restrict__ ktvT,
    float* __restrict__ out, float scale)
{
    const int chunk = blockIdx.x, head = blockIdx.y;
    const int n0 = chunk * (Nn / 16);               // 512 rows per block
    const float* Qp = Q + ((size_t)head * Nn + n0) * Dn;
    float* Op = out + ((size_t)head * Nn + n0) * Dn;
    const ushort* kp = ktvT + (size_t)head * (Dn * Dn);

    const int t = threadIdx.x, w = t >> 6, l = t & 63;
    const int lr = l & 15;          // A row-local / B col-local
    const int lg = l >> 4;          // k-group

    bf16x8 bf[4][2];
    #pragma unroll
    for (int E = 0; E < 4; ++E)
        #pragma unroll
        for (int h = 0; h < 2; ++h)
            bf[E][h] = *(const bf16x8*)&kp[(16 * E + lr) * 64 + 32 * h + 8 * lg];

    for (int i = 0; i < 8; ++i) {
        const int strip = i * 4 + w;                // 0..31, 16 rows each
        const float* qrow = Qp + (size_t)(strip * 16 + lr) * Dn;
        const float4 f0 = *(const float4*)(qrow + 8 * lg);
        const float4 f1 = *(const float4*)(qrow + 8 * lg + 4);
        const float4 f2 = *(const float4*)(qrow + 32 + 8 * lg);
        const float4 f3 = *(const float4*)(qrow + 32 + 8 * lg + 4);

        float ss = f0.x*f0.x + f0.y*f0.y + f0.z*f0.z + f0.w*f0.w
                 + f1.x*f1.x + f1.y*f1.y + f1.z*f1.z + f1.w*f1.w
                 + f2.x*f2.x + f2.y*f2.y + f2.z*f2.z + f2.w*f2.w
                 + f3.x*f3.x + f3.y*f3.y + f3.z*f3.z + f3.w*f3.w;
        ss += __shfl_xor(ss, 16, 64);
        ss += __shfl_xor(ss, 32, 64);
        const float inv = scale / fmaxf(sqrtf(ss), 1e-12f);

        union { unsigned u[4]; bf16x8 v; } a0, a1;
        a0.u[0] = cvt_pk_bf16(f0.x*inv, f0.y*inv);
        a0.u[1] = cvt_pk_bf16(f0.z*inv, f0.w*inv);
        a0.u[2] = cvt_pk_bf16(f1.x*inv, f1.y*inv);
        a0.u[3] = cvt_pk_bf16(f1.z*inv, f1.w*inv);
        a1.u[0] = cvt_pk_bf16(f2.x*inv, f2.y*inv);
        a1.u[1] = cvt_pk_bf16(f2.z*inv, f2.w*inv);
        a1.u[2] = cvt_pk_bf16(f3.x*inv, f3.y*inv);
        a1.u[3] = cvt_pk_bf16(f3.z*inv, f3.w*inv);

        #pragma unroll
        for (int E = 0; E < 4; ++E) {
            f32x4 c = {0.f, 0.f, 0.f, 0.f};
            c = __builtin_amdgcn_mfma_f32_16x16x32_bf16(a0.v, bf[E][0], c, 0, 0, 0);
            c = __builtin_amdgcn_mfma_f32_16x16x32_bf16(a1.v, bf[E][1], c, 0, 0, 0);
            #pragma unroll
            for (int r = 0; r < 4; ++r)
                Op[(size_t)(strip * 16 + 4 * lg + r) * Dn + 16 * E + lr] = c[r];
        }
    }
}

extern "C" void kernel_launch(void* const* d_in, const int* in_sizes, int n_in,
                              void* d_out, int out_size, void* d_ws, size_t ws_size,
                              hipStream_t stream)
{
    const float* Q    = (const float*)d_in[0];
    const float* K    = (const float*)d_in[1];
    const float* V    = (const float*)d_in[2];
    const float* mask = (const float*)d_in[3];
    float* out = (float*)d_out;

    const float scale = 1.0f / sqrtf(sqrtf((float)Nn));

    // ws layout: [ ktvT bf16: BH*4096 ushort ][ partial: BH*ch*4096 f32 ]
    const size_t KTV_BYTES = (size_t)BH * Dn * Dn * sizeof(ushort);   // 384 KB
    int ch = 64;
    while (ch > 1 &&
           KTV_BYTES + (size_t)BH * ch * Dn * Dn * 4 > ws_size)
        ch >>= 1;

    ushort* ktvT   = (ushort*)d_ws;
    float* partial = (float*)((char*)d_ws + KTV_BYTES);

    ktv_kernel<<<dim3(ch, BH), 256, 0, stream>>>(K, V, mask, partial, scale, ch);
    ktv_reduce_kernel<<<dim3((Dn * Dn) / 256, BH), 256, 0, stream>>>(partial, ktvT, ch);
    qktv_kernel<<<dim3(16, BH), 256, 0, stream>>>(Q, ktvT, out, scale);
}

// Round 10
// 101.237 us; speedup vs baseline: 1.1419x; 1.1419x over previous
//
#include <hip/hip_runtime.h>
#include <cmath>

#define Bn 4
#define Hn 12
#define BH 48
#define Nn 8192
#define Dn 64

typedef float f32x4 __attribute__((ext_vector_type(4)));
typedef short bf16x8 __attribute__((ext_vector_type(8)));

__device__ __forceinline__ int swz(int d) { return ((d >> 2) & 7) << 3; }

// v_cvt_pk_bf16_f32: D[15:0]=bf16(lo), D[31:16]=bf16(hi)  (RNE)
__device__ __forceinline__ unsigned cvt_pk_bf16(float lo, float hi) {
    unsigned r;
    asm("v_cvt_pk_bf16_f32 %0, %1, %2" : "=v"(r) : "v"(lo), "v"(hi));
    return r;
}

// ---------------- Phase 1: partial KtV^T[e][d] = sum_n (rf*k)[n,d] * v[n,e] --
// Round-3 template (verified correct), amortized: each barrier period stages a
// 128-row PAIR (two 64-row halves, 32 KB LDS) with ONE pre/post __syncthreads
// pair, then runs 16 MFMAs. Periods per block 8->4; prefetch issued after the
// post-barrier has a 2x longer shadow before its drain at the next pre-barrier.
__global__ __launch_bounds__(256) void ktv_kernel(
    const float* __restrict__ K, const float* __restrict__ V,
    const float* __restrict__ mask, float* __restrict__ partial,
    float scale, int ch)
{
    const int chunk = blockIdx.x, head = blockIdx.y;
    const int bb = head / Hn;
    const int rowsPer = Nn / ch;              // 512 @ ch=16
    const int n0 = chunk * rowsPer;
    const float* Kp = K + ((size_t)head * Nn + n0) * Dn;
    const float* Vp = V + ((size_t)head * Nn + n0) * Dn;
    const float* mp = mask + (size_t)bb * Nn + n0;

    __shared__ __align__(16) ushort sKT[2][64 * 64];   // [half][d][n^swz(d)]
    __shared__ __align__(16) ushort sVT[2][64 * 64];   // [half][e][n^swz(e)]

    const int t = threadIdx.x;
    const int w = t >> 6, l = t & 63;
    const int g = t >> 4;            // staging row-group 0..15 (rows 4g..4g+3)
    const int c4 = (t & 15) << 2;    // staging d base

    f32x4 acc[4] = {{0.f,0.f,0.f,0.f},{0.f,0.f,0.f,0.f},
                    {0.f,0.f,0.f,0.f},{0.f,0.f,0.f,0.f}};

    float4 kr[2][4], vr[2][4];
    float mk[2][4];
    #pragma unroll
    for (int hh = 0; hh < 2; ++hh)
        #pragma unroll
        for (int s = 0; s < 4; ++s) {
            kr[hh][s] = *(const float4*)(Kp + (size_t)(hh * 64 + 4*g + s) * Dn + c4);
            vr[hh][s] = *(const float4*)(Vp + (size_t)(hh * 64 + 4*g + s) * Dn + c4);
            mk[hh][s] = mp[hh * 64 + 4*g + s];
        }

    const int nper = rowsPer >> 7;            // 128-row periods (4 @ ch=16)
    for (int pp = 0; pp < nper; ++pp) {
        // rf for both halves (round-3 body, [hh]-indexed)
        float rf[2][4];
        #pragma unroll
        for (int hh = 0; hh < 2; ++hh)
            #pragma unroll
            for (int s = 0; s < 4; ++s) {
                float ss = kr[hh][s].x*kr[hh][s].x + kr[hh][s].y*kr[hh][s].y
                         + kr[hh][s].z*kr[hh][s].z + kr[hh][s].w*kr[hh][s].w;
                #pragma unroll
                for (int off = 1; off < 16; off <<= 1) ss += __shfl_xor(ss, off, 64);
                rf[hh][s] = scale * mk[hh][s] * mk[hh][s] / fmaxf(sqrtf(ss), 1e-12f);
            }

        __syncthreads();                      // previous period fully consumed
        #pragma unroll
        for (int hh = 0; hh < 2; ++hh) {
            const float* krf = (const float*)kr[hh];
            const float* vrf = (const float*)vr[hh];
            #pragma unroll
            for (int j = 0; j < 4; ++j) {
                const int d = c4 + j;
                const int base = d * 64;
                const int sw = swz(d);
                const int p0 = (4*g)     ^ sw;    // swz hits bits 3..5 only
                const int p2 = (4*g + 2) ^ sw;
                *(unsigned*)&sKT[hh][base + p0] = cvt_pk_bf16(krf[j]     * rf[hh][0], krf[4+j]  * rf[hh][1]);
                *(unsigned*)&sKT[hh][base + p2] = cvt_pk_bf16(krf[8+j]   * rf[hh][2], krf[12+j] * rf[hh][3]);
                *(unsigned*)&sVT[hh][base + p0] = cvt_pk_bf16(vrf[j],            vrf[4+j]);
                *(unsigned*)&sVT[hh][base + p2] = cvt_pk_bf16(vrf[8+j],          vrf[12+j]);
            }
        }
        __syncthreads();

        if (pp + 1 < nper) {                  // prefetch next 128-row pair
            const float* Kn = Kp + (size_t)(pp + 1) * 128 * Dn;
            const float* Vn = Vp + (size_t)(pp + 1) * 128 * Dn;
            #pragma unroll
            for (int hh = 0; hh < 2; ++hh)
                #pragma unroll
                for (int s = 0; s < 4; ++s) {
                    kr[hh][s] = *(const float4*)(Kn + (size_t)(hh * 64 + 4*g + s) * Dn + c4);
                    vr[hh][s] = *(const float4*)(Vn + (size_t)(hh * 64 + 4*g + s) * Dn + c4);
                    mk[hh][s] = mp[(pp + 1) * 128 + hh * 64 + 4*g + s];
                }
        }

        // MFMA both halves: wave w owns e-strip [16w,16w+16)
        const int e   = (w << 4) + (l & 15);
        const int nsl = (l >> 4) << 3;
        const int swe = swz(e);
        #pragma unroll
        for (int hh = 0; hh < 2; ++hh)
            #pragma unroll
            for (int h = 0; h < 2; ++h) {
                const bf16x8 a = *(const bf16x8*)&sVT[hh][e * 64 + ((h*32 + nsl) ^ swe)];
                #pragma unroll
                for (int P = 0; P < 4; ++P) {
                    const int d = (P << 4) + (l & 15);
                    const bf16x8 bq = *(const bf16x8*)&sKT[hh][d * 64 + ((h*32 + nsl) ^ swz(d))];
                    acc[P] = __builtin_amdgcn_mfma_f32_16x16x32_bf16(a, bq, acc[P], 0, 0, 0);
                }
            }
    }

    // C layout: col = lane&15, row = 4*(lane>>4)+reg  (HW-verified, round 3)
    float* pp2 = partial + (size_t)(head * ch + chunk) * (Dn * Dn);
    #pragma unroll
    for (int P = 0; P < 4; ++P)
        #pragma unroll
        for (int r = 0; r < 4; ++r)
            pp2[((w << 4) + ((l >> 4) << 2) + r) * 64 + (P << 4) + (l & 15)] = acc[P][r];
}

// ---------------- Phase 1b: reduce partials, emit bf16 KtV^T ----------------
__global__ __launch_bounds__(256) void ktv_reduce_kernel(
    const float* __restrict__ partial, ushort* __restrict__ ktvT, int ch)
{
    const int head = blockIdx.y;
    const int e = blockIdx.x * 256 + threadIdx.x;   // 0..4095
    const float* pp = partial + (size_t)head * ch * (Dn * Dn) + e;
    float s = 0.f;
    for (int c = 0; c < ch; ++c) s += pp[(size_t)c * (Dn * Dn)];
    unsigned u = __float_as_uint(s);
    u = (u + 0x7fffu + ((u >> 16) & 1u)) >> 16;     // RNE
    ktvT[(size_t)head * (Dn * Dn) + e] = (ushort)u;
}

// ---------------- Phase 2: Out = (inv(n)*q) @ KtV  (no LDS) -----------------
__global__ __launch_bounds__(256) void qktv_kernel(
    const float* __restrict__ Q, const ushort* __restrict__ ktvT,
    float* __restrict__ out, float scale)
{
    const int chunk = blockIdx.x, head = blockIdx.y;
    const int n0 = chunk * (Nn / 16);               // 512 rows per block
    const float* Qp = Q + ((size_t)head * Nn + n0) * Dn;
    float* Op = out + ((size_t)head * Nn + n0) * Dn;
    const ushort* kp = ktvT + (size_t)head * (Dn * Dn);

    const int t = threadIdx.x, w = t >> 6, l = t & 63;
    const int lr = l & 15;          // A row-local / B col-local
    const int lg = l >> 4;          // k-group

    bf16x8 bf[4][2];
    #pragma unroll
    for (int E = 0; E < 4; ++E)
        #pragma unroll
        for (int h = 0; h < 2; ++h)
            bf[E][h] = *(const bf16x8*)&kp[(16 * E + lr) * 64 + 32 * h + 8 * lg];

    for (int i = 0; i < 8; ++i) {
        const int strip = i * 4 + w;                // 0..31, 16 rows each
        const float* qrow = Qp + (size_t)(strip * 16 + lr) * Dn;
        const float4 f0 = *(const float4*)(qrow + 8 * lg);
        const float4 f1 = *(const float4*)(qrow + 8 * lg + 4);
        const float4 f2 = *(const float4*)(qrow + 32 + 8 * lg);
        const float4 f3 = *(const float4*)(qrow + 32 + 8 * lg + 4);

        float ss = f0.x*f0.x + f0.y*f0.y + f0.z*f0.z + f0.w*f0.w
                 + f1.x*f1.x + f1.y*f1.y + f1.z*f1.z + f1.w*f1.w
                 + f2.x*f2.x + f2.y*f2.y + f2.z*f2.z + f2.w*f2.w
                 + f3.x*f3.x + f3.y*f3.y + f3.z*f3.z + f3.w*f3.w;
        ss += __shfl_xor(ss, 16, 64);
        ss += __shfl_xor(ss, 32, 64);
        const float inv = scale / fmaxf(sqrtf(ss), 1e-12f);

        union { unsigned u[4]; bf16x8 v; } a0, a1;
        a0.u[0] = cvt_pk_bf16(f0.x*inv, f0.y*inv);
        a0.u[1] = cvt_pk_bf16(f0.z*inv, f0.w*inv);
        a0.u[2] = cvt_pk_bf16(f1.x*inv, f1.y*inv);
        a0.u[3] = cvt_pk_bf16(f1.z*inv, f1.w*inv);
        a1.u[0] = cvt_pk_bf16(f2.x*inv, f2.y*inv);
        a1.u[1] = cvt_pk_bf16(f2.z*inv, f2.w*inv);
        a1.u[2] = cvt_pk_bf16(f3.x*inv, f3.y*inv);
        a1.u[3] = cvt_pk_bf16(f3.z*inv, f3.w*inv);

        #pragma unroll
        for (int E = 0; E < 4; ++E) {
            f32x4 c = {0.f, 0.f, 0.f, 0.f};
            c = __builtin_amdgcn_mfma_f32_16x16x32_bf16(a0.v, bf[E][0], c, 0, 0, 0);
            c = __builtin_amdgcn_mfma_f32_16x16x32_bf16(a1.v, bf[E][1], c, 0, 0, 0);
            #pragma unroll
            for (int r = 0; r < 4; ++r)
                Op[(size_t)(strip * 16 + 4 * lg + r) * Dn + 16 * E + lr] = c[r];
        }
    }
}

extern "C" void kernel_launch(void* const* d_in, const int* in_sizes, int n_in,
                              void* d_out, int out_size, void* d_ws, size_t ws_size,
                              hipStream_t stream)
{
    const float* Q    = (const float*)d_in[0];
    const float* K    = (const float*)d_in[1];
    const float* V    = (const float*)d_in[2];
    const float* mask = (const float*)d_in[3];
    float* out = (float*)d_out;

    const float scale = 1.0f / sqrtf(sqrtf((float)Nn));

    // ws layout: [ ktvT bf16: BH*4096 ushort ][ partial: BH*ch*4096 f32 ]
    const size_t KTV_BYTES = (size_t)BH * Dn * Dn * sizeof(ushort);   // 384 KB
    int ch = 16;
    while (ch > 1 &&
           KTV_BYTES + (size_t)BH * ch * Dn * Dn * 4 > ws_size)
        ch >>= 1;

    ushort* ktvT   = (ushort*)d_ws;
    float* partial = (float*)((char*)d_ws + KTV_BYTES);

    ktv_kernel<<<dim3(ch, BH), 256, 0, stream>>>(K, V, mask, partial, scale, ch);
    ktv_reduce_kernel<<<dim3((Dn * Dn) / 256, BH), 256, 0, stream>>>(partial, ktvT, ch);
    qktv_kernel<<<dim3(16, BH), 256, 0, stream>>>(Q, ktvT, out, scale);
}